// Round 8
// baseline (139.008 us; speedup 1.0000x reference)
//
#include <hip/hip_runtime.h>
#include <hip/hip_bf16.h>
#include <cstdint>

#define ALPHA 0.2f
#define NEG_INF -9000000000000000.0f
// B=8, N=1024, Din=Dout=256, M = 8192
// ws layout:
//   WhT bf16 [8][256][1024]   @ 0        (4 MiB)   B^T layout for MFMA B-frags
//   src  f32 [8192]           @ 4 MiB
//   dst  f32 [8192]           @ 4 MiB + 32 KiB

typedef __bf16 bf16_t;
typedef __bf16 bf16x8 __attribute__((ext_vector_type(8)));
typedef float f32x16 __attribute__((ext_vector_type(16)));

// ---------------- Kernel 1: WhT[b][f][j] = bf16( sum_d W[f][d] h[bj][d] ) via MFMA ----------------
__global__ __launch_bounds__(256) void k_gemm1(
    const float* __restrict__ h, const float* __restrict__ W, bf16_t* __restrict__ WhT)
{
  __shared__ bf16_t WS[64 * 72];   // [f_local][d_chunk], stride 72
  __shared__ bf16_t HS[64 * 72];   // [j_local][d_chunk]
  const int bx = blockIdx.x;
  const int b  = bx & 7;
  const int jt = (bx >> 3) & 15;
  const int ft = bx >> 7;
  const int j0 = jt * 64, f0 = ft * 64;
  const int t = threadIdx.x;
  const int w = t >> 6, lane = t & 63;
  const int mrow = lane & 31, half = lane >> 5;
  const int fsub = (w & 1) * 32, jsub = (w >> 1) * 32;

  const int lr = t >> 2;          // 0..63 (row)
  const int lc = (t & 3) * 16;    // 0,16,32,48 (col group)
  const float* wp = W + ((size_t)(f0 + lr)) * 256 + lc;
  const float* hp = h + ((size_t)(b * 1024 + j0 + lr)) * 256 + lc;

  f32x16 acc;
#pragma unroll
  for (int r = 0; r < 16; r++) acc[r] = 0.f;

  for (int s = 0; s < 4; s++) {
    if (s) __syncthreads();
    {
      float4 w0 = *(const float4*)(wp + s * 64);
      float4 w1 = *(const float4*)(wp + s * 64 + 4);
      float4 w2 = *(const float4*)(wp + s * 64 + 8);
      float4 w3 = *(const float4*)(wp + s * 64 + 12);
      bf16x8 va, vb;
      va[0] = (bf16_t)w0.x; va[1] = (bf16_t)w0.y; va[2] = (bf16_t)w0.z; va[3] = (bf16_t)w0.w;
      va[4] = (bf16_t)w1.x; va[5] = (bf16_t)w1.y; va[6] = (bf16_t)w1.z; va[7] = (bf16_t)w1.w;
      vb[0] = (bf16_t)w2.x; vb[1] = (bf16_t)w2.y; vb[2] = (bf16_t)w2.z; vb[3] = (bf16_t)w2.w;
      vb[4] = (bf16_t)w3.x; vb[5] = (bf16_t)w3.y; vb[6] = (bf16_t)w3.z; vb[7] = (bf16_t)w3.w;
      *(bf16x8*)&WS[lr * 72 + lc] = va;
      *(bf16x8*)&WS[lr * 72 + lc + 8] = vb;
      float4 h0 = *(const float4*)(hp + s * 64);
      float4 h1 = *(const float4*)(hp + s * 64 + 4);
      float4 h2 = *(const float4*)(hp + s * 64 + 8);
      float4 h3 = *(const float4*)(hp + s * 64 + 12);
      bf16x8 vc, vd;
      vc[0] = (bf16_t)h0.x; vc[1] = (bf16_t)h0.y; vc[2] = (bf16_t)h0.z; vc[3] = (bf16_t)h0.w;
      vc[4] = (bf16_t)h1.x; vc[5] = (bf16_t)h1.y; vc[6] = (bf16_t)h1.z; vc[7] = (bf16_t)h1.w;
      vd[0] = (bf16_t)h2.x; vd[1] = (bf16_t)h2.y; vd[2] = (bf16_t)h2.z; vd[3] = (bf16_t)h2.w;
      vd[4] = (bf16_t)h3.x; vd[5] = (bf16_t)h3.y; vd[6] = (bf16_t)h3.z; vd[7] = (bf16_t)h3.w;
      *(bf16x8*)&HS[lr * 72 + lc] = vc;
      *(bf16x8*)&HS[lr * 72 + lc + 8] = vd;
    }
    __syncthreads();
#pragma unroll
    for (int ks = 0; ks < 4; ks++) {
      bf16x8 af = *(const bf16x8*)&WS[(fsub + mrow) * 72 + ks * 16 + half * 8];
      bf16x8 bf = *(const bf16x8*)&HS[(jsub + mrow) * 72 + ks * 16 + half * 8];
      acc = __builtin_amdgcn_mfma_f32_32x32x16_bf16(af, bf, acc, 0, 0, 0);
    }
  }

  // D: col(j)=lane&31, row(f)=(reg&3)+8*(reg>>2)+4*half
  const int jcol = j0 + jsub + mrow;
#pragma unroll
  for (int r = 0; r < 16; r++) {
    int frow = fsub + (r & 3) + 8 * (r >> 2) + 4 * half;
    WhT[(((size_t)(b * 256 + f0 + frow)) << 10) + jcol] = (bf16_t)acc[r];
  }
}

// ---------------- Kernel 2: u = W^T a (per-block) then src/dst GEMV (fp32 exact) ----------------
__global__ __launch_bounds__(256) void k_src(
    const float* __restrict__ h, const float* __restrict__ W, const float* __restrict__ a,
    float* __restrict__ src, float* __restrict__ dst)
{
  __shared__ float uS[512];
  const int t = threadIdx.x;
  {
    float s1a = 0.f, s1b = 0.f, s2a = 0.f, s2b = 0.f;
#pragma unroll 4
    for (int f = 0; f < 256; f += 2) {
      float w0 = W[f * 256 + t];
      float w1 = W[(f + 1) * 256 + t];
      s1a = fmaf(w0, a[f], s1a);       s1b = fmaf(w1, a[f + 1], s1b);
      s2a = fmaf(w0, a[256 + f], s2a); s2b = fmaf(w1, a[256 + f + 1], s2b);
    }
    uS[t] = s1a + s1b; uS[256 + t] = s2a + s2b;
  }
  __syncthreads();
  const int n = t >> 4, c = t & 15;
  const int m = blockIdx.x * 16 + n;
  const float* hp = h + (size_t)m * 256 + c * 16;
  float s1 = 0.f, s2 = 0.f;
#pragma unroll
  for (int i = 0; i < 4; i++) {
    float4 v = *(const float4*)(hp + i * 4);
    const float* u1p = &uS[c * 16 + i * 4];
    const float* u2p = &uS[256 + c * 16 + i * 4];
    s1 = fmaf(v.x, u1p[0], s1); s1 = fmaf(v.y, u1p[1], s1);
    s1 = fmaf(v.z, u1p[2], s1); s1 = fmaf(v.w, u1p[3], s1);
    s2 = fmaf(v.x, u2p[0], s2); s2 = fmaf(v.y, u2p[1], s2);
    s2 = fmaf(v.z, u2p[2], s2); s2 = fmaf(v.w, u2p[3], s2);
  }
#pragma unroll
  for (int off = 8; off; off >>= 1) {
    s1 += __shfl_down(s1, off, 16);
    s2 += __shfl_down(s2, off, 16);
  }
  if (c == 0) { src[m] = s1; dst[m] = s2; }
}

// ---------------- Kernel 3: fused P-compute (adj direct) + MFMA + ones-column row sums ----------------
// grid 512 = b(8) x fhalf(2) x itile(32). 4 waves; wave w owns f-tile fh*128 + w*32.
// P chunk (32 i x 256 j) in LDS dbuf; B-frags direct from global WhT (L2-resident, b-swizzle).
// acc2 += P * ones gives per-lane row sums in the SAME register rows as acc -> barrier-free normalize.
__global__ __launch_bounds__(256) void k_fused(
    const bf16_t* __restrict__ WhT, const int* __restrict__ adj,
    const float* __restrict__ src, const float* __restrict__ dst,
    float* __restrict__ out)
{
  const int b  = blockIdx.x & 7;
  const int fh = (blockIdx.x >> 3) & 1;
  const int i0 = (blockIdx.x >> 4) << 5;
  const int t  = threadIdx.x;
  const int w  = t >> 6;
  const int lane = t & 63;
  const int mrow = lane & 31, half = lane >> 5;

  __shared__ float dstS[1024];
  __shared__ float srcS[32];
  __shared__ bf16_t P[2][32 * 264];   // double buffer, stride 264 (conflict-free b128)

  *(float4*)&dstS[t * 4] = *(const float4*)(dst + (b << 10) + t * 4);
  if (t < 32) srcS[t] = src[(b << 10) + i0 + t];
  __syncthreads();

  f32x16 acc, acc2;
#pragma unroll
  for (int r = 0; r < 16; r++) { acc[r] = 0.f; acc2[r] = 0.f; }

  bf16x8 ones;
#pragma unroll
  for (int k = 0; k < 8; k++) ones[k] = (bf16_t)1.0f;

  // lane's B-frag row: f = fh*128 + w*32 + mrow
  const bf16_t* bp = WhT + (((size_t)(b * 256 + fh * 128 + w * 32 + mrow)) << 10);
  const int* arow = adj + ((((size_t)(b << 10)) + i0) << 10) + t;   // row i0, col t

  for (int c = 0; c < 4; c++) {
    bf16_t* Pc = &P[c & 1][0];
    {
      float dj = dstS[c * 256 + t];
      const int* ac = arow + c * 256;
#pragma unroll 8
      for (int i = 0; i < 32; i++) {
        int av = ac[(size_t)i << 10];              // adj[b][i0+i][c*256+t], coalesced over t
        float v = srcS[i] + dj;
        float vl = fmaxf(v, ALPHA * v);
        float e = (av > 0) ? vl : NEG_INF;
        Pc[i * 264 + t] = (bf16_t)__expf(e);       // exp(NEG_INF) == 0
      }
    }
    __syncthreads();

    const bf16_t* bpc = bp + c * 256 + half * 8;
    const bf16_t* prow = Pc + mrow * 264 + half * 8;
#pragma unroll
    for (int idx = 0; idx < 16; idx++) {
      bf16x8 afr = *(const bf16x8*)(prow + idx * 16);
      bf16x8 bfr = *(const bf16x8*)(bpc + idx * 16);
      acc  = __builtin_amdgcn_mfma_f32_32x32x16_bf16(afr, bfr, acc, 0, 0, 0);
      acc2 = __builtin_amdgcn_mfma_f32_32x32x16_bf16(afr, ones, acc2, 0, 0, 0);
    }
  }

  // D: col=lane&31, row=(reg&3)+8*(reg>>2)+4*half ; acc2[r] = rowsum(P) for that same row
  const int col = fh * 128 + w * 32 + mrow;
#pragma unroll
  for (int r = 0; r < 16; r++) {
    int row = (r & 3) + 8 * (r >> 2) + 4 * half;
    out[((size_t)(b << 10) + i0 + row) * 256 + col] = acc[r] / acc2[r];
  }
}

// ---------------- Launch ----------------
extern "C" void kernel_launch(void* const* d_in, const int* in_sizes, int n_in,
                              void* d_out, int out_size, void* d_ws, size_t ws_size,
                              hipStream_t stream) {
  const float* h   = (const float*)d_in[0];
  const int*   adj = (const int*)d_in[1];
  const float* W   = (const float*)d_in[2];
  const float* a   = (const float*)d_in[3];
  float* out = (float*)d_out;

  char* wsb = (char*)d_ws;
  bf16_t* WhT = (bf16_t*)wsb;
  float* srcv = (float*)(wsb + (4u << 20));
  float* dstv = srcv + 8192;

  k_src  <<<512, 256, 0, stream>>>(h, W, a, srcv, dstv);
  k_gemm1<<<512, 256, 0, stream>>>(h, W, WhT);
  k_fused<<<512, 256, 0, stream>>>(WhT, adj, srcv, dstv, out);
}

// Round 9
// 122.859 us; speedup vs baseline: 1.1314x; 1.1314x over previous
//
#include <hip/hip_runtime.h>
#include <hip/hip_bf16.h>
#include <cstdint>

#define ALPHA 0.2f
#define NEG_INF -9000000000000000.0f
// B=8, N=1024, Din=Dout=256, M = 8192
// ws layout:
//   WhT bf16 [8][256][1024]   @ 0        (4 MiB)   B^T layout for MFMA B-frags
//   src  f32 [8192]           @ 4 MiB
//   dst  f32 [8192]           @ 4 MiB + 32 KiB
//   mask u64 [8192][16]       @ 4 MiB + 64 KiB   (1 MiB)

typedef __bf16 bf16_t;
typedef __bf16 bf16x8 __attribute__((ext_vector_type(8)));
typedef float f32x16 __attribute__((ext_vector_type(16)));

// ---------------- Kernel 1: two roles ----------------
// bx < 512 : WhT = bf16(h @ W^T) transposed, via MFMA (R6 k_gemm1 verbatim)
// bx >= 512: u = W^T a ; src/dst GEMV (fp32) ; adj -> bitmask (16 rows/block)
__global__ __launch_bounds__(256) void k_pre(
    const float* __restrict__ h, const float* __restrict__ W, const float* __restrict__ a,
    const int* __restrict__ adj, bf16_t* __restrict__ WhT,
    float* __restrict__ src, float* __restrict__ dst,
    unsigned long long* __restrict__ mask_ws)
{
  __shared__ __align__(16) char smem[64 * 72 * 2 * sizeof(bf16_t)];
  const int bx = blockIdx.x;
  const int t = threadIdx.x;

  if (bx < 512) {
    // ================= GEMM role =================
    bf16_t* WS = (bf16_t*)smem;          // [f_local][d_chunk], stride 72
    bf16_t* HS = WS + 64 * 72;           // [j_local][d_chunk]
    const int b  = bx & 7;
    const int jt = (bx >> 3) & 15;
    const int ft = bx >> 7;
    const int j0 = jt * 64, f0 = ft * 64;
    const int w = t >> 6, lane = t & 63;
    const int mrow = lane & 31, half = lane >> 5;
    const int fsub = (w & 1) * 32, jsub = (w >> 1) * 32;

    const int lr = t >> 2;          // 0..63 (row)
    const int lc = (t & 3) * 16;    // 0,16,32,48 (col group)
    const float* wp = W + ((size_t)(f0 + lr)) * 256 + lc;
    const float* hp = h + ((size_t)(b * 1024 + j0 + lr)) * 256 + lc;

    f32x16 acc;
#pragma unroll
    for (int r = 0; r < 16; r++) acc[r] = 0.f;

    for (int s = 0; s < 4; s++) {
      if (s) __syncthreads();
      {
        float4 w0 = *(const float4*)(wp + s * 64);
        float4 w1 = *(const float4*)(wp + s * 64 + 4);
        float4 w2 = *(const float4*)(wp + s * 64 + 8);
        float4 w3 = *(const float4*)(wp + s * 64 + 12);
        bf16x8 va, vb;
        va[0] = (bf16_t)w0.x; va[1] = (bf16_t)w0.y; va[2] = (bf16_t)w0.z; va[3] = (bf16_t)w0.w;
        va[4] = (bf16_t)w1.x; va[5] = (bf16_t)w1.y; va[6] = (bf16_t)w1.z; va[7] = (bf16_t)w1.w;
        vb[0] = (bf16_t)w2.x; vb[1] = (bf16_t)w2.y; vb[2] = (bf16_t)w2.z; vb[3] = (bf16_t)w2.w;
        vb[4] = (bf16_t)w3.x; vb[5] = (bf16_t)w3.y; vb[6] = (bf16_t)w3.z; vb[7] = (bf16_t)w3.w;
        *(bf16x8*)&WS[lr * 72 + lc] = va;
        *(bf16x8*)&WS[lr * 72 + lc + 8] = vb;
        float4 h0 = *(const float4*)(hp + s * 64);
        float4 h1 = *(const float4*)(hp + s * 64 + 4);
        float4 h2 = *(const float4*)(hp + s * 64 + 8);
        float4 h3 = *(const float4*)(hp + s * 64 + 12);
        bf16x8 vc, vd;
        vc[0] = (bf16_t)h0.x; vc[1] = (bf16_t)h0.y; vc[2] = (bf16_t)h0.z; vc[3] = (bf16_t)h0.w;
        vc[4] = (bf16_t)h1.x; vc[5] = (bf16_t)h1.y; vc[6] = (bf16_t)h1.z; vc[7] = (bf16_t)h1.w;
        vd[0] = (bf16_t)h2.x; vd[1] = (bf16_t)h2.y; vd[2] = (bf16_t)h2.z; vd[3] = (bf16_t)h2.w;
        vd[4] = (bf16_t)h3.x; vd[5] = (bf16_t)h3.y; vd[6] = (bf16_t)h3.z; vd[7] = (bf16_t)h3.w;
        *(bf16x8*)&HS[lr * 72 + lc] = vc;
        *(bf16x8*)&HS[lr * 72 + lc + 8] = vd;
      }
      __syncthreads();
#pragma unroll
      for (int ks = 0; ks < 4; ks++) {
        bf16x8 af = *(const bf16x8*)&WS[(fsub + mrow) * 72 + ks * 16 + half * 8];
        bf16x8 bf = *(const bf16x8*)&HS[(jsub + mrow) * 72 + ks * 16 + half * 8];
        acc = __builtin_amdgcn_mfma_f32_32x32x16_bf16(af, bf, acc, 0, 0, 0);
      }
    }

    // D: col(j)=lane&31, row(f)=(reg&3)+8*(reg>>2)+4*half
    const int jcol = j0 + jsub + mrow;
#pragma unroll
    for (int r = 0; r < 16; r++) {
      int frow = fsub + (r & 3) + 8 * (r >> 2) + 4 * half;
      WhT[(((size_t)(b * 256 + f0 + frow)) << 10) + jcol] = (bf16_t)acc[r];
    }
  } else {
    // ================= PREP role: u, src/dst, masks for 16 rows =================
    float* uS = (float*)smem;            // [512]
    const int p  = bx - 512;             // 0..511
    const int m0 = p * 16;
    {
      float s1a = 0.f, s1b = 0.f, s2a = 0.f, s2b = 0.f;
#pragma unroll 4
      for (int f = 0; f < 256; f += 2) {
        float w0 = W[f * 256 + t];
        float w1 = W[(f + 1) * 256 + t];
        s1a = fmaf(w0, a[f], s1a);       s1b = fmaf(w1, a[f + 1], s1b);
        s2a = fmaf(w0, a[256 + f], s2a); s2b = fmaf(w1, a[256 + f + 1], s2b);
      }
      uS[t] = s1a + s1b; uS[256 + t] = s2a + s2b;
    }
    __syncthreads();
    {
      const int n = t >> 4, c = t & 15;
      const int m = m0 + n;
      const float* hp = h + (size_t)m * 256 + c * 16;
      float s1 = 0.f, s2 = 0.f;
#pragma unroll
      for (int i = 0; i < 4; i++) {
        float4 v = *(const float4*)(hp + i * 4);
        const float* u1p = &uS[c * 16 + i * 4];
        const float* u2p = &uS[256 + c * 16 + i * 4];
        s1 = fmaf(v.x, u1p[0], s1); s1 = fmaf(v.y, u1p[1], s1);
        s1 = fmaf(v.z, u1p[2], s1); s1 = fmaf(v.w, u1p[3], s1);
        s2 = fmaf(v.x, u2p[0], s2); s2 = fmaf(v.y, u2p[1], s2);
        s2 = fmaf(v.z, u2p[2], s2); s2 = fmaf(v.w, u2p[3], s2);
      }
#pragma unroll
      for (int off = 8; off; off >>= 1) {
        s1 += __shfl_down(s1, off, 16);
        s2 += __shfl_down(s2, off, 16);
      }
      if (c == 0) { src[m] = s1; dst[m] = s2; }
    }
    // mask build: word (row, wv*4+k) bit lane = adj[row][256*wv + 4*lane + k]
    {
      const int wv = t >> 6, lane = t & 63;
#pragma unroll 4
      for (int r = 0; r < 16; r++) {
        const size_t row = (size_t)(m0 + r);
        const int4 av = *(const int4*)(adj + (row << 10) + 4 * t);
        unsigned long long b0 = __ballot(av.x > 0);
        unsigned long long b1 = __ballot(av.y > 0);
        unsigned long long b2 = __ballot(av.z > 0);
        unsigned long long b3 = __ballot(av.w > 0);
        if (lane == 0) {
          unsigned long long* mp = mask_ws + row * 16 + wv * 4;
          mp[0] = b0; mp[1] = b1; mp[2] = b2; mp[3] = b3;
        }
      }
    }
  }
}

// ---------------- Kernel 2: P = exp(e) (bf16, LDS dbuf) + MFMA + ones-MFMA normalize ----------------
// grid 512 = b(8) x fhalf(2) x itile(32). 4 waves; wave w owns f-tile fh*128 + w*32.
// B-frags direct from global WhT (L2-resident, b-swizzle). acc2 += P*ones -> per-lane row sums.
__global__ __launch_bounds__(256) void k_attn(
    const bf16_t* __restrict__ WhT, const float* __restrict__ src, const float* __restrict__ dst,
    const unsigned long long* __restrict__ mask_ws, float* __restrict__ out)
{
  const int b  = blockIdx.x & 7;
  const int fh = (blockIdx.x >> 3) & 1;
  const int i0 = (blockIdx.x >> 4) << 5;
  const int t  = threadIdx.x;
  const int w  = t >> 6;
  const int lane = t & 63;
  const int mrow = lane & 31, half = lane >> 5;

  __shared__ float dstS[1024];
  __shared__ float srcS[32];
  __shared__ unsigned long long maskS[32 * 16];
  __shared__ bf16_t P[2][32 * 264];   // double buffer, stride 264 (conflict-free b128)

  *(float4*)&dstS[t * 4] = *(const float4*)(dst + (b << 10) + t * 4);
  if (t < 32) srcS[t] = src[(b << 10) + i0 + t];
  {
    const size_t mb = ((size_t)(b << 10) + i0) * 16;
    maskS[t]       = mask_ws[mb + t];
    maskS[t + 256] = mask_ws[mb + t + 256];
  }
  __syncthreads();

  f32x16 acc, acc2;
#pragma unroll
  for (int r = 0; r < 16; r++) { acc[r] = 0.f; acc2[r] = 0.f; }

  bf16x8 ones;
#pragma unroll
  for (int k = 0; k < 8; k++) ones[k] = (bf16_t)1.0f;

  // lane's B-frag row: f = fh*128 + w*32 + mrow
  const bf16_t* bp = WhT + (((size_t)(b * 256 + fh * 128 + w * 32 + mrow)) << 10);

  for (int c = 0; c < 4; c++) {
    bf16_t* Pc = &P[c & 1][0];
    {
      float dj = dstS[c * 256 + t];
      int mi = c * 4 + (t & 3);    // word index
      int sh = t >> 2;             // bit position
#pragma unroll 8
      for (int i = 0; i < 32; i++) {
        unsigned long long w64 = maskS[i * 16 + mi];
        float v = srcS[i] + dj;
        float vl = fmaxf(v, ALPHA * v);
        float e = ((w64 >> sh) & 1ull) ? vl : NEG_INF;
        Pc[i * 264 + t] = (bf16_t)__expf(e);   // exp(NEG_INF) == 0
      }
    }
    __syncthreads();

    const bf16_t* bpc = bp + c * 256 + half * 8;
    const bf16_t* prow = Pc + mrow * 264 + half * 8;
#pragma unroll
    for (int idx = 0; idx < 16; idx++) {
      bf16x8 afr = *(const bf16x8*)(prow + idx * 16);
      bf16x8 bfr = *(const bf16x8*)(bpc + idx * 16);
      acc  = __builtin_amdgcn_mfma_f32_32x32x16_bf16(afr, bfr, acc, 0, 0, 0);
      acc2 = __builtin_amdgcn_mfma_f32_32x32x16_bf16(afr, ones, acc2, 0, 0, 0);
    }
  }

  // D: col=lane&31, row=(reg&3)+8*(reg>>2)+4*half ; acc2[r] = rowsum(P) for the same row
  const int col = fh * 128 + w * 32 + mrow;
#pragma unroll
  for (int r = 0; r < 16; r++) {
    int row = (r & 3) + 8 * (r >> 2) + 4 * half;
    out[((size_t)(b << 10) + i0 + row) * 256 + col] = acc[r] / acc2[r];
  }
}

// ---------------- Launch ----------------
extern "C" void kernel_launch(void* const* d_in, const int* in_sizes, int n_in,
                              void* d_out, int out_size, void* d_ws, size_t ws_size,
                              hipStream_t stream) {
  const float* h   = (const float*)d_in[0];
  const int*   adj = (const int*)d_in[1];
  const float* W   = (const float*)d_in[2];
  const float* a   = (const float*)d_in[3];
  float* out = (float*)d_out;

  char* wsb = (char*)d_ws;
  bf16_t* WhT = (bf16_t*)wsb;
  float* srcv = (float*)(wsb + (4u << 20));
  float* dstv = srcv + 8192;
  unsigned long long* mask_ws = (unsigned long long*)(wsb + (4u << 20) + 65536);

  k_pre <<<1024, 256, 0, stream>>>(h, W, a, adj, WhT, srcv, dstv, mask_ws);
  k_attn<<<512,  256, 0, stream>>>(WhT, srcv, dstv, mask_ws, out);
}

// Round 10
// 121.135 us; speedup vs baseline: 1.1476x; 1.0142x over previous
//
#include <hip/hip_runtime.h>
#include <hip/hip_bf16.h>
#include <cstdint>

#define ALPHA 0.2f
#define NEG_INF -9000000000000000.0f
// B=8, N=1024, Din=Dout=256, M = 8192
// ws layout:
//   WhT bf16 [8][256][1024]   @ 0        (4 MiB)   B^T layout for MFMA B-frags
//   src  f32 [8192]           @ 4 MiB
//   dst  f32 [8192]           @ 4 MiB + 32 KiB
//   mask u64 [8192][16]       @ 4 MiB + 64 KiB   (1 MiB)

typedef __bf16 bf16_t;
typedef __bf16 bf16x8 __attribute__((ext_vector_type(8)));
typedef float f32x16 __attribute__((ext_vector_type(16)));

// ---------------- Kernel 1: two roles (R9 verbatim) ----------------
// bx < 512 : WhT = bf16(h @ W^T) transposed, via MFMA
// bx >= 512: u = W^T a ; src/dst GEMV (fp32) ; adj -> bitmask (16 rows/block)
__global__ __launch_bounds__(256) void k_pre(
    const float* __restrict__ h, const float* __restrict__ W, const float* __restrict__ a,
    const int* __restrict__ adj, bf16_t* __restrict__ WhT,
    float* __restrict__ src, float* __restrict__ dst,
    unsigned long long* __restrict__ mask_ws)
{
  __shared__ __align__(16) char smem[64 * 72 * 2 * sizeof(bf16_t)];
  const int bx = blockIdx.x;
  const int t = threadIdx.x;

  if (bx < 512) {
    // ================= GEMM role =================
    bf16_t* WS = (bf16_t*)smem;          // [f_local][d_chunk], stride 72
    bf16_t* HS = WS + 64 * 72;           // [j_local][d_chunk]
    const int b  = bx & 7;
    const int jt = (bx >> 3) & 15;
    const int ft = bx >> 7;
    const int j0 = jt * 64, f0 = ft * 64;
    const int w = t >> 6, lane = t & 63;
    const int mrow = lane & 31, half = lane >> 5;
    const int fsub = (w & 1) * 32, jsub = (w >> 1) * 32;

    const int lr = t >> 2;          // 0..63 (row)
    const int lc = (t & 3) * 16;    // 0,16,32,48 (col group)
    const float* wp = W + ((size_t)(f0 + lr)) * 256 + lc;
    const float* hp = h + ((size_t)(b * 1024 + j0 + lr)) * 256 + lc;

    f32x16 acc;
#pragma unroll
    for (int r = 0; r < 16; r++) acc[r] = 0.f;

    for (int s = 0; s < 4; s++) {
      if (s) __syncthreads();
      {
        float4 w0 = *(const float4*)(wp + s * 64);
        float4 w1 = *(const float4*)(wp + s * 64 + 4);
        float4 w2 = *(const float4*)(wp + s * 64 + 8);
        float4 w3 = *(const float4*)(wp + s * 64 + 12);
        bf16x8 va, vb;
        va[0] = (bf16_t)w0.x; va[1] = (bf16_t)w0.y; va[2] = (bf16_t)w0.z; va[3] = (bf16_t)w0.w;
        va[4] = (bf16_t)w1.x; va[5] = (bf16_t)w1.y; va[6] = (bf16_t)w1.z; va[7] = (bf16_t)w1.w;
        vb[0] = (bf16_t)w2.x; vb[1] = (bf16_t)w2.y; vb[2] = (bf16_t)w2.z; vb[3] = (bf16_t)w2.w;
        vb[4] = (bf16_t)w3.x; vb[5] = (bf16_t)w3.y; vb[6] = (bf16_t)w3.z; vb[7] = (bf16_t)w3.w;
        *(bf16x8*)&WS[lr * 72 + lc] = va;
        *(bf16x8*)&WS[lr * 72 + lc + 8] = vb;
        float4 h0 = *(const float4*)(hp + s * 64);
        float4 h1 = *(const float4*)(hp + s * 64 + 4);
        float4 h2 = *(const float4*)(hp + s * 64 + 8);
        float4 h3 = *(const float4*)(hp + s * 64 + 12);
        bf16x8 vc, vd;
        vc[0] = (bf16_t)h0.x; vc[1] = (bf16_t)h0.y; vc[2] = (bf16_t)h0.z; vc[3] = (bf16_t)h0.w;
        vc[4] = (bf16_t)h1.x; vc[5] = (bf16_t)h1.y; vc[6] = (bf16_t)h1.z; vc[7] = (bf16_t)h1.w;
        vd[0] = (bf16_t)h2.x; vd[1] = (bf16_t)h2.y; vd[2] = (bf16_t)h2.z; vd[3] = (bf16_t)h2.w;
        vd[4] = (bf16_t)h3.x; vd[5] = (bf16_t)h3.y; vd[6] = (bf16_t)h3.z; vd[7] = (bf16_t)h3.w;
        *(bf16x8*)&HS[lr * 72 + lc] = vc;
        *(bf16x8*)&HS[lr * 72 + lc + 8] = vd;
      }
      __syncthreads();
#pragma unroll
      for (int ks = 0; ks < 4; ks++) {
        bf16x8 af = *(const bf16x8*)&WS[(fsub + mrow) * 72 + ks * 16 + half * 8];
        bf16x8 bf = *(const bf16x8*)&HS[(jsub + mrow) * 72 + ks * 16 + half * 8];
        acc = __builtin_amdgcn_mfma_f32_32x32x16_bf16(af, bf, acc, 0, 0, 0);
      }
    }

    // D: col(j)=lane&31, row(f)=(reg&3)+8*(reg>>2)+4*half
    const int jcol = j0 + jsub + mrow;
#pragma unroll
    for (int r = 0; r < 16; r++) {
      int frow = fsub + (r & 3) + 8 * (r >> 2) + 4 * half;
      WhT[(((size_t)(b * 256 + f0 + frow)) << 10) + jcol] = (bf16_t)acc[r];
    }
  } else {
    // ================= PREP role: u, src/dst, masks for 16 rows =================
    float* uS = (float*)smem;            // [512]
    const int p  = bx - 512;             // 0..511
    const int m0 = p * 16;
    {
      float s1a = 0.f, s1b = 0.f, s2a = 0.f, s2b = 0.f;
#pragma unroll 4
      for (int f = 0; f < 256; f += 2) {
        float w0 = W[f * 256 + t];
        float w1 = W[(f + 1) * 256 + t];
        s1a = fmaf(w0, a[f], s1a);       s1b = fmaf(w1, a[f + 1], s1b);
        s2a = fmaf(w0, a[256 + f], s2a); s2b = fmaf(w1, a[256 + f + 1], s2b);
      }
      uS[t] = s1a + s1b; uS[256 + t] = s2a + s2b;
    }
    __syncthreads();
    {
      const int n = t >> 4, c = t & 15;
      const int m = m0 + n;
      const float* hp = h + (size_t)m * 256 + c * 16;
      float s1 = 0.f, s2 = 0.f;
#pragma unroll
      for (int i = 0; i < 4; i++) {
        float4 v = *(const float4*)(hp + i * 4);
        const float* u1p = &uS[c * 16 + i * 4];
        const float* u2p = &uS[256 + c * 16 + i * 4];
        s1 = fmaf(v.x, u1p[0], s1); s1 = fmaf(v.y, u1p[1], s1);
        s1 = fmaf(v.z, u1p[2], s1); s1 = fmaf(v.w, u1p[3], s1);
        s2 = fmaf(v.x, u2p[0], s2); s2 = fmaf(v.y, u2p[1], s2);
        s2 = fmaf(v.z, u2p[2], s2); s2 = fmaf(v.w, u2p[3], s2);
      }
#pragma unroll
      for (int off = 8; off; off >>= 1) {
        s1 += __shfl_down(s1, off, 16);
        s2 += __shfl_down(s2, off, 16);
      }
      if (c == 0) { src[m] = s1; dst[m] = s2; }
    }
    // mask build: word (row, wv*4+k) bit lane = adj[row][256*wv + 4*lane + k]
    {
      const int wv = t >> 6, lane = t & 63;
#pragma unroll 4
      for (int r = 0; r < 16; r++) {
        const size_t row = (size_t)(m0 + r);
        const int4 av = *(const int4*)(adj + (row << 10) + 4 * t);
        unsigned long long b0 = __ballot(av.x > 0);
        unsigned long long b1 = __ballot(av.y > 0);
        unsigned long long b2 = __ballot(av.z > 0);
        unsigned long long b3 = __ballot(av.w > 0);
        if (lane == 0) {
          unsigned long long* mp = mask_ws + row * 16 + wv * 4;
          mp[0] = b0; mp[1] = b1; mp[2] = b2; mp[3] = b3;
        }
      }
    }
  }
}

// ---------------- Kernel 2: factored-exp P + MFMA + ones-MFMA normalize ----------------
// 256 blocks = b(8) x itile(32); 512 threads = 8 waves; wave w owns f-tile w*32 (all 256 f).
// P_ij = bit ? ((Esi*Edj > 1) ? Esi*Edj : Fsi*Fdj) : 0   — no per-edge transcendental.
// P chunk computed ONCE per (b,itile) (vs twice in the fh-split scheme).
__global__ __launch_bounds__(512) void k_attn(
    const bf16_t* __restrict__ WhT, const float* __restrict__ src, const float* __restrict__ dst,
    const unsigned long long* __restrict__ mask_ws, float* __restrict__ out)
{
  const int b  = blockIdx.x & 7;
  const int i0 = (blockIdx.x >> 3) << 5;
  const int t  = threadIdx.x;            // 0..511
  const int w  = t >> 6;                 // wave 0..7
  const int lane = t & 63;
  const int mrow = lane & 31, half = lane >> 5;

  __shared__ float dstE[1024], dstF[1024];
  __shared__ float srcE[32], srcF[32];
  __shared__ unsigned long long maskS[32 * 16];
  __shared__ bf16_t P[2][32 * 264];      // double buffer, stride 264 (conflict-free b128)

  {
    float2 d2 = *(const float2*)(dst + (b << 10) + t * 2);
    dstE[t * 2]     = __expf(d2.x);  dstF[t * 2]     = __expf(ALPHA * d2.x);
    dstE[t * 2 + 1] = __expf(d2.y);  dstF[t * 2 + 1] = __expf(ALPHA * d2.y);
  }
  if (t < 32) {
    float s = src[(b << 10) + i0 + t];
    srcE[t] = __expf(s);  srcF[t] = __expf(ALPHA * s);
  }
  maskS[t] = mask_ws[((size_t)(b << 10) + i0) * 16 + t];   // exactly 512 words
  __syncthreads();

  f32x16 acc, acc2;
#pragma unroll
  for (int r = 0; r < 16; r++) { acc[r] = 0.f; acc2[r] = 0.f; }

  bf16x8 ones;
#pragma unroll
  for (int k = 0; k < 8; k++) ones[k] = (bf16_t)1.0f;

  // lane's B-frag row: f = w*32 + mrow
  const bf16_t* bp = WhT + (((size_t)(b * 256 + w * 32 + mrow)) << 10);
  const int jj = t & 255, ih = t >> 8;   // P-compute role: column jj, i-half ih

  for (int c = 0; c < 4; c++) {
    bf16_t* Pc = &P[c & 1][0];
    {
      float Edj = dstE[c * 256 + jj];
      float Fdj = dstF[c * 256 + jj];
      int mi = c * 4 + (jj & 3);         // word index
      int sh = jj >> 2;                  // bit position
#pragma unroll
      for (int r = 0; r < 16; r++) {
        int i = ih * 16 + r;
        unsigned long long w64 = maskS[i * 16 + mi];
        float pp = srcE[i] * Edj;
        float pn = srcF[i] * Fdj;
        float p = (pp > 1.0f) ? pp : pn;           // leaky-relu branch via product
        p = ((w64 >> sh) & 1ull) ? p : 0.0f;       // adjacency mask
        Pc[i * 264 + jj] = (bf16_t)p;
      }
    }
    __syncthreads();

    const bf16_t* bpc = bp + c * 256 + half * 8;
    const bf16_t* prow = Pc + mrow * 264 + half * 8;
#pragma unroll
    for (int idx = 0; idx < 16; idx++) {
      bf16x8 afr = *(const bf16x8*)(prow + idx * 16);
      bf16x8 bfr = *(const bf16x8*)(bpc + idx * 16);
      acc  = __builtin_amdgcn_mfma_f32_32x32x16_bf16(afr, bfr, acc, 0, 0, 0);
      acc2 = __builtin_amdgcn_mfma_f32_32x32x16_bf16(afr, ones, acc2, 0, 0, 0);
    }
  }

  // D: col=lane&31, row=(reg&3)+8*(reg>>2)+4*half ; acc2[r] = rowsum(P) for the same row
  const int col = w * 32 + mrow;
#pragma unroll
  for (int r = 0; r < 16; r++) {
    int row = (r & 3) + 8 * (r >> 2) + 4 * half;
    out[((size_t)(b << 10) + i0 + row) * 256 + col] = acc[r] / acc2[r];
  }
}

// ---------------- Launch ----------------
extern "C" void kernel_launch(void* const* d_in, const int* in_sizes, int n_in,
                              void* d_out, int out_size, void* d_ws, size_t ws_size,
                              hipStream_t stream) {
  const float* h   = (const float*)d_in[0];
  const int*   adj = (const int*)d_in[1];
  const float* W   = (const float*)d_in[2];
  const float* a   = (const float*)d_in[3];
  float* out = (float*)d_out;

  char* wsb = (char*)d_ws;
  bf16_t* WhT = (bf16_t*)wsb;
  float* srcv = (float*)(wsb + (4u << 20));
  float* dstv = srcv + 8192;
  unsigned long long* mask_ws = (unsigned long long*)(wsb + (4u << 20) + 65536);

  k_pre <<<1024, 256, 0, stream>>>(h, W, a, adj, WhT, srcv, dstv, mask_ws);
  k_attn<<<256,  512, 0, stream>>>(WhT, srcv, dstv, mask_ws, out);
}